// Round 15
// baseline (419.582 us; speedup 1.0000x reference)
//
#include <hip/hip_runtime.h>

#define N_NODES 50000
#define DIM     256
#define R_REL   4
#define E_EDGES 500000
#define NV_VUL  10000
#define K_CAND  8
#define EPS_C   1e-8f
#define RN      (R_REL * N_NODES)            // 200000
#define NB      196                          // buckets per relation (256 nodes each)
#define TB      (R_REL * NB)                 // 784 total buckets
#define BCAP    5120                         // capacity per bucket (mean 2551)
#define EPB     4096                         // edges per bin block
#define PREP_W   80                          // convert_w blocks
#define PREP_BIN ((R_REL * E_EDGES + EPB - 1) / EPB)   // 489

typedef short bf16x8 __attribute__((ext_vector_type(8)));
typedef float f32x4  __attribute__((ext_vector_type(4)));
typedef float f32x2  __attribute__((ext_vector_type(2)));
typedef unsigned short us8 __attribute__((ext_vector_type(8)));
typedef unsigned int u32x4 __attribute__((ext_vector_type(4)));

__device__ __forceinline__ unsigned short f2bf_rne(float f) {
  unsigned u = __builtin_bit_cast(unsigned, f);
  unsigned r = (u + 0x7FFFu + ((u >> 16) & 1u)) >> 16;
  return (unsigned short)r;
}
__device__ __forceinline__ float bf2f(unsigned short h) {
  unsigned u = ((unsigned)h) << 16;
  return __builtin_bit_cast(float, u);
}
// one dword holding 2 bf16 -> float2 {elem_lo, elem_hi}
__device__ __forceinline__ f32x2 expand_bf2(unsigned dw) {
  f32x2 v;
  v.x = __builtin_bit_cast(float, dw << 16);
  v.y = __builtin_bit_cast(float, dw & 0xFFFF0000u);
  return v;
}
__device__ __forceinline__ bf16x8 cvt8hi(float4 a, float4 b) {
  float f[8] = {a.x, a.y, a.z, a.w, b.x, b.y, b.z, b.w};
  bf16x8 hh;
#pragma unroll
  for (int i = 0; i < 8; i++) hh[i] = (short)f2bf_rne(f[i]);
  return hh;
}

// ---- fused prep: convert_w | bin, partitioned by blockIdx.x ----
__global__ __launch_bounds__(1024) void k_prep(const float* __restrict__ Wn,
                                               const float* __restrict__ We,
                                               short* __restrict__ Bthi,
                                               const int* __restrict__ src,
                                               const int* __restrict__ dst,
                                               int* __restrict__ cursor,
                                               int* __restrict__ binned) {
  __shared__ float tile[64][65];
  __shared__ int hist[TB];
  __shared__ int base[TB];
  int blk = blockIdx.x;
  int tid = threadIdx.x;

  if (blk < PREP_W) {
    // ---- weight transpose+convert: Bthi[w][n][k] = bf16(W_w[k][n]) ----
    int w   = blk / 16;
    int rem = blk % 16;
    int k0  = (rem / 4) * 64, n0 = (rem % 4) * 64;
    const float* W = (w == 0) ? Wn : We + (size_t)(w - 1) * 65536;
    int tx = tid & 63, ty = tid >> 6;            // ty: 0..15
    for (int i = ty; i < 64; i += 16)
      tile[i][tx] = W[(size_t)(k0 + i) * 256 + n0 + tx];
    __syncthreads();
    for (int i = ty; i < 64; i += 16) {
      float f = tile[tx][i];                     // = W[k0+tx][n0+i]
      size_t o = (size_t)w * 65536 + (size_t)(n0 + i) * 256 + k0 + tx;
      Bthi[o] = (short)f2bf_rne(f);
    }
    return;
  }
  // ---- bin edges into TB coarse buckets; packed entry = (src<<8)|(dst&255) ----
  int bb = blk - PREP_W;
  for (int i = tid; i < TB; i += 1024) hist[i] = 0;
  __syncthreads();
  int e0 = bb * EPB;
  int myb[4], myrank[4], myp[4];
#pragma unroll
  for (int i = 0; i < 4; i++) {
    int e = e0 + i * 1024 + tid;
    myb[i] = -1;
    if (e < R_REL * E_EDGES) {
      int r = e / E_EDGES;
      int d = dst[e];
      int s = src[e];
      int b = r * NB + (d >> 8);
      myb[i]    = b;
      myp[i]    = (s << 8) | (d & 255);
      myrank[i] = atomicAdd(&hist[b], 1);
    }
  }
  __syncthreads();
  for (int i = tid; i < TB; i += 1024) {
    int c = hist[i];
    base[i] = c ? atomicAdd(&cursor[i], c) : 0;
  }
  __syncthreads();
#pragma unroll
  for (int i = 0; i < 4; i++) {
    if (myb[i] >= 0) {
      int pos = base[myb[i]] + myrank[i];
      if (pos < BCAP) binned[(size_t)myb[i] * BCAP + pos] = myp[i];
    }
  }
}

#define GR  64    // rows per block
#define GBK 32
// ---- all 5 GEMMs, A staged ONCE per block (fp32 -> bf16 in-register), loop w.
// 64 rows x 256 cols, 4 waves (each wave owns 64 cols). rn fused per w.
__global__ __launch_bounds__(256) void k_gemm_all(const float* __restrict__ x,
                                                  const short* __restrict__ Bthi_all,
                                                  const float* __restrict__ bnb,
                                                  unsigned short* __restrict__ ht16,
                                                  unsigned short* __restrict__ hr0,
                                                  unsigned short* __restrict__ hr1,
                                                  unsigned short* __restrict__ hr2,
                                                  unsigned short* __restrict__ hr3,
                                                  float* __restrict__ rn_all,
                                                  int M) {
  __shared__ short A_s[GR][264];      // 264*2=528B row stride (16B-aligned)
  __shared__ short B_s[256][40];      // 80B row stride (16B-aligned)
  __shared__ float nsq_s[GR];
  const int t    = threadIdx.x;       // 0..255
  const int bm0  = blockIdx.x * GR;
  const int lane = t & 63;
  const int wn   = (t >> 6) * 64;     // wave's 64-col slice
  const int m16  = lane & 15, kg = lane >> 4;

  // stage A once: 64 rows x 256 K, fp32 -> bf16
  for (int i = t; i < GR * 32; i += 256) {     // us8 chunks
    int row = i >> 5, c = i & 31;
    int gr = bm0 + row; if (gr >= M) gr = M - 1;
    const float* xp = x + (size_t)gr * 256 + c * 8;
    float4 a = *(const float4*)xp;
    float4 b = *(const float4*)(xp + 4);
    *(bf16x8*)&A_s[row][c * 8] = cvt8hi(a, b);
  }

  unsigned short* Cs[5] = {ht16, hr0, hr1, hr2, hr3};

#pragma unroll 1
  for (int w = 0; w < 5; w++) {
    const short* Bthi = Bthi_all + (size_t)w * 65536;
    unsigned short* C16 = Cs[w];
    float* rn = rn_all + (size_t)w * N_NODES;

    if (t < GR) nsq_s[t] = 0.f;
    __syncthreads();                   // A_s ready (w=0) / prev B_s reads done

    f32x4 acc[4][4] = {};
    for (int k0 = 0; k0 < DIM; k0 += GBK) {
      // stage B chunk: 256 cols x 32 K
      for (int i = t; i < 1024; i += 256) {    // us8 chunks
        int n = i >> 2, c = i & 3;
        *(bf16x8*)&B_s[n][c * 8] = *(const bf16x8*)(Bthi + (size_t)n * 256 + k0 + c * 8);
      }
      __syncthreads();

      bf16x8 ah[4], bh[4];
#pragma unroll
      for (int i = 0; i < 4; i++) {
        ah[i] = *(const bf16x8*)&A_s[i * 16 + m16][k0 + kg * 8];
        bh[i] = *(const bf16x8*)&B_s[wn + i * 16 + m16][kg * 8];
      }
#pragma unroll
      for (int mi = 0; mi < 4; mi++)
#pragma unroll
        for (int ni = 0; ni < 4; ni++)
          acc[mi][ni] = __builtin_amdgcn_mfma_f32_16x16x32_bf16(ah[mi], bh[ni], acc[mi][ni], 0, 0, 0);
      __syncthreads();
    }

    // epilogue: bias, store bf16 C, per-row sumsq via LDS
#pragma unroll
    for (int mi = 0; mi < 4; mi++) {
      float ps[4] = {0.f, 0.f, 0.f, 0.f};
#pragma unroll
      for (int ni = 0; ni < 4; ni++) {
        int col = wn + ni * 16 + m16;
        float bb = (w == 0) ? bnb[col] : 0.f;
        f32x4 v = acc[mi][ni];
#pragma unroll
        for (int j = 0; j < 4; j++) {
          float vj = v[j] + bb;
          int row = bm0 + mi * 16 + kg * 4 + j;
          if (row < M) C16[(size_t)row * 256 + col] = f2bf_rne(vj);
          ps[j] += vj * vj;
        }
      }
#pragma unroll
      for (int j = 0; j < 4; j++) {
        float s = ps[j];
        s += __shfl_xor(s, 1);
        s += __shfl_xor(s, 2);
        s += __shfl_xor(s, 4);
        s += __shfl_xor(s, 8);
        if (m16 == 0) atomicAdd(&nsq_s[mi * 16 + kg * 4 + j], s);
      }
    }
    __syncthreads();
    if (t < GR) {
      int row = bm0 + t;
      if (row < M) rn[row] = fminf(rsqrtf(nsq_s[t]), 1e8f);
    }
  }
}

// ---- scan of TB bucket counts -> global bucket bases; also offsets[RN] ----
__global__ __launch_bounds__(1024) void k_bucket_scan(const int* __restrict__ cnt,
                                                      int* __restrict__ bbase,
                                                      int* __restrict__ offsets) {
  __shared__ int s[1024];
  int tid = threadIdx.x;
  int v = (tid < TB) ? cnt[tid] : 0;
  s[tid] = v;
  __syncthreads();
  for (int off = 1; off < 1024; off <<= 1) {
    int t2 = (tid >= off) ? s[tid - off] : 0;
    __syncthreads();
    s[tid] += t2;
    __syncthreads();
  }
  if (tid < TB) bbase[tid] = s[tid] - v;
  if (tid == TB - 1) offsets[RN] = s[tid];
}

// ---- per-bucket exact CSR (offsets + edge_src) ----
__global__ __launch_bounds__(256) void k_csr(const int* __restrict__ binned,
                                             const int* __restrict__ cnt_arr,
                                             const int* __restrict__ bbase,
                                             int* __restrict__ offsets,
                                             int* __restrict__ edge_src) {
  __shared__ int hist[256];
  __shared__ int excl[256];
  int b   = blockIdx.x;
  int tid = threadIdx.x;
  int cnt = cnt_arr[b]; if (cnt > BCAP) cnt = BCAP;
  int gbase = bbase[b];
  hist[tid] = 0;
  __syncthreads();
  const int* bp = binned + (size_t)b * BCAP;
  for (int i = tid; i < cnt; i += 256) atomicAdd(&hist[bp[i] & 255], 1);
  __syncthreads();
  int v = hist[tid];
  excl[tid] = v;
  __syncthreads();
  for (int off = 1; off < 256; off <<= 1) {
    int t2 = (tid >= off) ? excl[tid - off] : 0;
    __syncthreads();
    excl[tid] += t2;
    __syncthreads();
  }
  int ex = excl[tid] - v;                         // exclusive within bucket
  int r = b / NB, bloc = b % NB;
  int node = bloc * 256 + tid;
  if (node < N_NODES) offsets[r * N_NODES + node] = gbase + ex;
  hist[tid] = gbase + ex;                         // reuse as cursor
  __syncthreads();
  for (int i = tid; i < cnt; i += 256) {
    int p = bp[i];
    int pos = atomicAdd(&hist[p & 255], 1);
    edge_src[pos] = p >> 8;
  }
}

// ---- fused aggregation + final combine: one wave per dst node ----
// 16-lane group g owns relation g's edge list (1 edge/iter, 2-deep prefetch);
// lane owns 16 elements as 8 packed float2. For n>=NV the softmax combine is
// done in-register and written straight to out (non-temporal); h16/ma stored
// only for n<NV.
__global__ __launch_bounds__(256) void k_aggregate_fused(
    const unsigned short* __restrict__ hr0, const unsigned short* __restrict__ hr1,
    const unsigned short* __restrict__ hr2, const unsigned short* __restrict__ hr3,
    const unsigned short* __restrict__ ht16, const float* __restrict__ rn,
    const int* __restrict__ offsets, const int* __restrict__ edge_src,
    unsigned short* __restrict__ h16, float* __restrict__ ma,
    float* __restrict__ out) {
  int n    = (int)((blockIdx.x * (size_t)blockDim.x + threadIdx.x) >> 6);
  int lane = threadIdx.x & 63;
  if (n >= N_NODES) return;
  int g = lane >> 4, l16 = lane & 15;

  const u32x4* htp = (const u32x4*)(ht16 + (size_t)n * DIM + l16 * 16);
  u32x4 hta = __builtin_nontemporal_load(htp);
  u32x4 htb = __builtin_nontemporal_load(htp + 1);
  float rd = rn[n];
  f32x2 rd2 = {rd, rd};
  f32x2 hd2[8];
  hd2[0] = expand_bf2(hta[0]) * rd2; hd2[1] = expand_bf2(hta[1]) * rd2;
  hd2[2] = expand_bf2(hta[2]) * rd2; hd2[3] = expand_bf2(hta[3]) * rd2;
  hd2[4] = expand_bf2(htb[0]) * rd2; hd2[5] = expand_bf2(htb[1]) * rd2;
  hd2[6] = expand_bf2(htb[2]) * rd2; hd2[7] = expand_bf2(htb[3]) * rd2;

  const unsigned short* hr = (g == 0) ? hr0 : (g == 1) ? hr1 : (g == 2) ? hr2 : hr3;
  const float* nq = rn + (size_t)(1 + g) * N_NODES;
  int b   = offsets[g * N_NODES + n];
  int end = offsets[g * N_NODES + n + 1];

  f32x2 acc2[8] = {};
  float asum = 0.f;

  auto loadslot = [&](int i, uint4& ua, uint4& ub, float& q) {
    if (i < end) {
      int sn = edge_src[i];
      const uint4* rp = (const uint4*)(hr + (size_t)sn * DIM + l16 * 16);
      ua = rp[0]; ub = rp[1];
      q  = nq[sn];
    }
  };
  auto consume = [&](uint4 ua, uint4 ub, float q, bool valid) {
    f32x2 hs2[8];
    hs2[0] = expand_bf2(ua.x); hs2[1] = expand_bf2(ua.y);
    hs2[2] = expand_bf2(ua.z); hs2[3] = expand_bf2(ua.w);
    hs2[4] = expand_bf2(ub.x); hs2[5] = expand_bf2(ub.y);
    hs2[6] = expand_bf2(ub.z); hs2[7] = expand_bf2(ub.w);
    f32x2 d2 = hs2[0] * hd2[0];
#pragma unroll
    for (int i = 1; i < 8; i++) d2 += hs2[i] * hd2[i];
    float num = d2.x + d2.y;
    num += __shfl_xor(num, 1);
    num += __shfl_xor(num, 2);
    num += __shfl_xor(num, 4);
    num += __shfl_xor(num, 8);
    float s = valid ? num * q : 0.f;
    f32x2 s2 = {s, s};
#pragma unroll
    for (int i = 0; i < 8; i++) acc2[i] += hs2[i] * s2;
    asum += s;
  };

  uint4 uaA = {0,0,0,0}, ubA = {0,0,0,0}, uaB = {0,0,0,0}, ubB = {0,0,0,0};
  float qA = 1.f, qB = 1.f;
  loadslot(b,     uaA, ubA, qA);
  loadslot(b + 1, uaB, ubB, qB);
  for (int i = b; i < end; i += 2) {
    uint4 uaC = {0,0,0,0}, ubC = {0,0,0,0}, uaD = {0,0,0,0}, ubD = {0,0,0,0};
    float qC = 1.f, qD = 1.f;
    loadslot(i + 2, uaC, ubC, qC);
    loadslot(i + 3, uaD, ubD, qD);
    consume(uaA, ubA, qA, true);
    consume(uaB, ubB, qB, (i + 1) < end);
    uaA = uaC; ubA = ubC; qA = qC;
    uaB = uaD; ubB = ubD; qB = qD;
  }

  float mymean = asum / fmaxf((float)(end - b), 1.0f);

  if (n < NV_VUL) {
    us8 o1, o2;
#pragma unroll
    for (int i = 0; i < 4; i++) {
      o1[2 * i]     = f2bf_rne(acc2[i].x);
      o1[2 * i + 1] = f2bf_rne(acc2[i].y);
      o2[2 * i]     = f2bf_rne(acc2[4 + i].x);
      o2[2 * i + 1] = f2bf_rne(acc2[4 + i].y);
    }
    unsigned short* hp = h16 + ((size_t)n * R_REL + g) * DIM + l16 * 16;
    *(us8*)hp       = o1;
    *(us8*)(hp + 8) = o2;
    if (l16 == 0) ma[n * R_REL + g] = mymean;
  } else {
    // in-register softmax over the 4 groups' means
    float a1 = __shfl_xor(mymean, 16);
    float a2 = __shfl_xor(mymean, 32);
    float a3 = __shfl_xor(mymean, 48);
    float mx = fmaxf(fmaxf(mymean, a1), fmaxf(a2, a3));
    float e0 = expf(mymean - mx);
    float denom = e0 + expf(a1 - mx) + expf(a2 - mx) + expf(a3 - mx);
    float w = e0 / denom;
    f32x2 o[8];
#pragma unroll
    for (int i = 0; i < 8; i++) {
      f32x2 v = acc2[i] * (f32x2){w, w};
      v.x += __shfl_xor(v.x, 16); v.x += __shfl_xor(v.x, 32);
      v.y += __shfl_xor(v.y, 16); v.y += __shfl_xor(v.y, 32);
      o[i] = v;
    }
    if (g == 0) {
      float* op = out + (size_t)n * 256 + l16 * 16;
      f32x4 v0 = {o[0].x, o[0].y, o[1].x, o[1].y};
      f32x4 v1 = {o[2].x, o[2].y, o[3].x, o[3].y};
      f32x4 v2 = {o[4].x, o[4].y, o[5].x, o[5].y};
      f32x4 v3 = {o[6].x, o[6].y, o[7].x, o[7].y};
      __builtin_nontemporal_store(v0, (f32x4*)(op + 0));
      __builtin_nontemporal_store(v1, (f32x4*)(op + 4));
      __builtin_nontemporal_store(v2, (f32x4*)(op + 8));
      __builtin_nontemporal_store(v3, (f32x4*)(op + 12));
    }
  }
}

// ------- vulnerable nodes: mask + combine from bf16 h16 (NV rows only) -------
__global__ __launch_bounds__(256) void k_vuln_combine(const unsigned short* __restrict__ h16,
                                                      const int* __restrict__ cand,
                                                      const float* __restrict__ ma,
                                                      float* __restrict__ out) {
  __shared__ float red[8][4];
  __shared__ float dist2s[8];
  __shared__ float sm[1024];
  int n   = blockIdx.x;
  int tid = threadIdx.x;                       // owns elements tid*4 .. tid*4+3
  ushort4 hb = *(const ushort4*)(h16 + (size_t)n * 1024 + tid * 4);
  float4 hv;
  hv.x = bf2f(hb.x); hv.y = bf2f(hb.y); hv.z = bf2f(hb.z); hv.w = bf2f(hb.w);
  float4 d2[8];
  int wid = tid >> 6, lane = tid & 63;
#pragma unroll
  for (int k = 0; k < 8; k++) {
    int c = cand[n * 8 + k];
    ushort4 cb = *(const ushort4*)(h16 + (size_t)c * 1024 + tid * 4);
    float4 df;
    df.x = hv.x - bf2f(cb.x); df.y = hv.y - bf2f(cb.y);
    df.z = hv.z - bf2f(cb.z); df.w = hv.w - bf2f(cb.w);
    d2[k].x = df.x * df.x; d2[k].y = df.y * df.y;
    d2[k].z = df.z * df.z; d2[k].w = df.w * df.w;
    float v = d2[k].x + d2[k].y + d2[k].z + d2[k].w;
    for (int off = 32; off; off >>= 1) v += __shfl_xor(v, off);
    if (lane == 0) red[k][wid] = v;
  }
  __syncthreads();
  if (tid < 32) {
    int k = tid >> 2, w2 = tid & 3;
    float v = red[k][w2];
    v += __shfl_xor(v, 1, 4);
    v += __shfl_xor(v, 2, 4);
    if (w2 == 0) dist2s[k] = v;
  }
  __syncthreads();
  float dk[8], mn = 1e30f;
#pragma unroll
  for (int k = 0; k < 8; k++) { dk[k] = sqrtf(dist2s[k]); mn = fminf(mn, dk[k]); }
  float se = 0.f, att[8];
#pragma unroll
  for (int k = 0; k < 8; k++) { att[k] = expf(mn - dk[k]); se += att[k]; }
  float inv = 1.f / se;
  float4 accv = {0.f, 0.f, 0.f, 0.f};
#pragma unroll
  for (int k = 0; k < 8; k++) {
    float a = att[k] * inv;
    accv.x += a * d2[k].x; accv.y += a * d2[k].y;
    accv.z += a * d2[k].z; accv.w += a * d2[k].w;
  }
  float m0 = ma[n * 4 + 0], m1 = ma[n * 4 + 1], m2 = ma[n * 4 + 2], m3 = ma[n * 4 + 3];
  float mx = fmaxf(fmaxf(m0, m1), fmaxf(m2, m3));
  float w0 = expf(m0 - mx), w1 = expf(m1 - mx), w2f = expf(m2 - mx), w3 = expf(m3 - mx);
  float winv = 1.f / (w0 + w1 + w2f + w3);
  float wr = (tid < 64) ? w0 : (tid < 128) ? w1 : (tid < 192) ? w2f : w3;
  float c = wr * winv;
  float4 o;
  o.x = c * hv.x * expf(-accv.x);
  o.y = c * hv.y * expf(-accv.y);
  o.z = c * hv.z * expf(-accv.z);
  o.w = c * hv.w * expf(-accv.w);
  *(float4*)&sm[tid * 4] = o;
  __syncthreads();
  if (tid < 256) {
    float v = sm[tid] + sm[256 + tid] + sm[512 + tid] + sm[768 + tid];
    __builtin_nontemporal_store(v, out + (size_t)n * 256 + tid);
  }
}

// ---------------- diagnostic fallback ----------------
__global__ void k_fallback(float* __restrict__ out, int out_size, float wsmb) {
  int i = blockIdx.x * blockDim.x + threadIdx.x;
  if (i < out_size) out[i] = (i == 0) ? wsmb : 0.f;
}

extern "C" void kernel_launch(void* const* d_in, const int* in_sizes, int n_in,
                              void* d_out, int out_size, void* d_ws, size_t ws_size,
                              hipStream_t stream) {
  const float* x   = (const float*)d_in[0];
  const float* We  = (const float*)d_in[1];
  const float* Wn  = (const float*)d_in[2];
  const float* bnb = (const float*)d_in[3];
  const int* src   = (const int*)d_in[4];
  const int* dst   = (const int*)d_in[5];
  const int* cand  = (const int*)d_in[6];
  float* out = (float*)d_out;

  char* ws = (char*)d_ws;
  size_t off = 0;
  auto alloc = [&](size_t bytes) -> void* {
    void* p = ws + off;
    off += (bytes + 255) & ~(size_t)255;
    return p;
  };
  unsigned short* ht16        = (unsigned short*)alloc((size_t)N_NODES * DIM * 2);          // 25.6 MB
  unsigned short* h16         = (unsigned short*)alloc((size_t)NV_VUL * R_REL * DIM * 2);   // 20.5 MB
  float*          ma          = (float*)alloc((size_t)NV_VUL * R_REL * 4);
  float*          rn          = (float*)alloc((size_t)5 * N_NODES * 4);                     // reciprocal norms
  int*            bucket_cnt  = (int*)alloc((size_t)TB * 4);
  int*            bucket_base = (int*)alloc((size_t)TB * 4);
  int*            offsets     = (int*)alloc((size_t)(RN + 1) * 4);
  int*            edge_src    = (int*)alloc((size_t)R_REL * E_EDGES * 4);                   // 8 MB
  short*          Bthi        = (short*)alloc((size_t)5 * 65536 * 2);                       // 0.66 MB
  unsigned short* hr0         = (unsigned short*)alloc((size_t)N_NODES * DIM * 2);          // 25.6 MB
  unsigned short* hr1         = (unsigned short*)alloc((size_t)N_NODES * DIM * 2);          // 25.6 MB
  unsigned short* hr2         = (unsigned short*)alloc((size_t)N_NODES * DIM * 2);          // 25.6 MB
  unsigned short* hr3         = (unsigned short*)alloc((size_t)N_NODES * DIM * 2);          // 25.6 MB
  size_t required = off;
  (void)in_sizes; (void)n_in;

  if (ws_size < required) {
    k_fallback<<<(out_size + 255) / 256, 256, 0, stream>>>(out, out_size,
                                                           (float)(ws_size >> 20));
    return;
  }

  int* binned = (int*)h16;       // 16.06 MB bin staging aliases h16 (dead before aggregate)

  hipMemsetAsync(bucket_cnt, 0, (size_t)TB * 4, stream);

  // fused prep: weight convert | edge binning
  k_prep<<<PREP_W + PREP_BIN, 1024, 0, stream>>>(Wn, We, Bthi, src, dst,
                                                 bucket_cnt, binned);
  k_bucket_scan<<<1, 1024, 0, stream>>>(bucket_cnt, bucket_base, offsets);
  k_csr<<<TB, 256, 0, stream>>>(binned, bucket_cnt, bucket_base, offsets, edge_src);

  // all 5 projections, A staged once per 64-row block (fp32 x read once).
  k_gemm_all<<<(N_NODES + GR - 1) / GR, 256, 0, stream>>>(x, Bthi, bnb, ht16,
                                                          hr0, hr1, hr2, hr3, rn, N_NODES);

  // fused aggregation + combine (writes h16/ma for n<NV, out rows [NV,N) directly)
  k_aggregate_fused<<<(N_NODES * 64 + 255) / 256, 256, 0, stream>>>(
      hr0, hr1, hr2, hr3, ht16, rn, offsets, edge_src, h16, ma, out);

  // vulnerable nodes: mask + combine (reads h16, writes out rows [0, NV))
  k_vuln_combine<<<NV_VUL, 256, 0, stream>>>(h16, cand, ma, out);
}

// Round 16
// 336.153 us; speedup vs baseline: 1.2482x; 1.2482x over previous
//
#include <hip/hip_runtime.h>

#define N_NODES 50000
#define DIM     256
#define R_REL   4
#define E_EDGES 500000
#define NV_VUL  10000
#define K_CAND  8
#define EPS_C   1e-8f
#define RN      (R_REL * N_NODES)            // 200000
#define NB      196                          // buckets per relation (256 nodes each)
#define TB      (R_REL * NB)                 // 784 total buckets
#define BCAP    5120                         // capacity per bucket (mean 2551)
#define EPB     4096                         // edges per bin block
#define PREP_W   80                          // convert_w blocks
#define PREP_X   128                         // convert_x blocks
#define PREP_BIN ((R_REL * E_EDGES + EPB - 1) / EPB)   // 489

typedef short bf16x8 __attribute__((ext_vector_type(8)));
typedef float f32x4  __attribute__((ext_vector_type(4)));
typedef float f32x2  __attribute__((ext_vector_type(2)));
typedef unsigned short us8 __attribute__((ext_vector_type(8)));
typedef unsigned int u32x4 __attribute__((ext_vector_type(4)));

__device__ __forceinline__ unsigned short f2bf_rne(float f) {
  unsigned u = __builtin_bit_cast(unsigned, f);
  unsigned r = (u + 0x7FFFu + ((u >> 16) & 1u)) >> 16;
  return (unsigned short)r;
}
__device__ __forceinline__ float bf2f(unsigned short h) {
  unsigned u = ((unsigned)h) << 16;
  return __builtin_bit_cast(float, u);
}
// one dword holding 2 bf16 -> float2 {elem_lo, elem_hi}
__device__ __forceinline__ f32x2 expand_bf2(unsigned dw) {
  f32x2 v;
  v.x = __builtin_bit_cast(float, dw << 16);
  v.y = __builtin_bit_cast(float, dw & 0xFFFF0000u);
  return v;
}

// ---- fused prep: convert_w | convert_x | bin, partitioned by blockIdx.x ----
__global__ __launch_bounds__(1024) void k_prep(const float* __restrict__ x,
                                               const float* __restrict__ Wn,
                                               const float* __restrict__ We,
                                               unsigned short* __restrict__ x16,
                                               short* __restrict__ Bthi,
                                               const int* __restrict__ src,
                                               const int* __restrict__ dst,
                                               int* __restrict__ cursor,
                                               int* __restrict__ binned) {
  __shared__ float tile[64][65];
  __shared__ int hist[TB];
  __shared__ int base[TB];
  int blk = blockIdx.x;
  int tid = threadIdx.x;

  if (blk < PREP_W) {
    // ---- weight transpose+convert: Bthi[w][n][k] = bf16(W_w[k][n]) ----
    int w   = blk / 16;
    int rem = blk % 16;
    int k0  = (rem / 4) * 64, n0 = (rem % 4) * 64;
    const float* W = (w == 0) ? Wn : We + (size_t)(w - 1) * 65536;
    int tx = tid & 63, ty = tid >> 6;            // ty: 0..15
    for (int i = ty; i < 64; i += 16)
      tile[i][tx] = W[(size_t)(k0 + i) * 256 + n0 + tx];
    __syncthreads();
    for (int i = ty; i < 64; i += 16) {
      float f = tile[tx][i];                     // = W[k0+tx][n0+i]
      size_t o = (size_t)w * 65536 + (size_t)(n0 + i) * 256 + k0 + tx;
      Bthi[o] = (short)f2bf_rne(f);
    }
    return;
  }
  if (blk < PREP_W + PREP_X) {
    // ---- x fp32 -> bf16 (grid-stride over us8 chunks) ----
    const int total = N_NODES * DIM / 8;
    for (int i = (blk - PREP_W) * 1024 + tid; i < total; i += PREP_X * 1024) {
      float4 a = *(const float4*)(x + (size_t)i * 8);
      float4 b = *(const float4*)(x + (size_t)i * 8 + 4);
      us8 o;
      o[0] = f2bf_rne(a.x); o[1] = f2bf_rne(a.y); o[2] = f2bf_rne(a.z); o[3] = f2bf_rne(a.w);
      o[4] = f2bf_rne(b.x); o[5] = f2bf_rne(b.y); o[6] = f2bf_rne(b.z); o[7] = f2bf_rne(b.w);
      *(us8*)(x16 + (size_t)i * 8) = o;
    }
    return;
  }
  // ---- bin edges into TB coarse buckets; packed entry = (src<<8)|(dst&255) ----
  int bb = blk - PREP_W - PREP_X;
  for (int i = tid; i < TB; i += 1024) hist[i] = 0;
  __syncthreads();
  int e0 = bb * EPB;
  int myb[4], myrank[4], myp[4];
#pragma unroll
  for (int i = 0; i < 4; i++) {
    int e = e0 + i * 1024 + tid;
    myb[i] = -1;
    if (e < R_REL * E_EDGES) {
      int r = e / E_EDGES;
      int d = dst[e];
      int s = src[e];
      int b = r * NB + (d >> 8);
      myb[i]    = b;
      myp[i]    = (s << 8) | (d & 255);
      myrank[i] = atomicAdd(&hist[b], 1);
    }
  }
  __syncthreads();
  for (int i = tid; i < TB; i += 1024) {
    int c = hist[i];
    base[i] = c ? atomicAdd(&cursor[i], c) : 0;
  }
  __syncthreads();
#pragma unroll
  for (int i = 0; i < 4; i++) {
    if (myb[i] >= 0) {
      int pos = base[myb[i]] + myrank[i];
      if (pos < BCAP) binned[(size_t)myb[i] * BCAP + pos] = myp[i];
    }
  }
}

#define GBM 128
#define GBK 32
// ---- all 5 GEMMs in one dispatch (z = weight index); 128x256 tile, 8 waves.
// Row sum-of-squares finished in LDS and written as reciprocal norm directly.
__global__ __launch_bounds__(512) void k_gemm_all(const unsigned short* __restrict__ A16,
                                                  const short* __restrict__ Bthi_all,
                                                  const float* __restrict__ bnb,
                                                  unsigned short* __restrict__ ht16,
                                                  unsigned short* __restrict__ hr0,
                                                  unsigned short* __restrict__ hr1,
                                                  unsigned short* __restrict__ hr2,
                                                  unsigned short* __restrict__ hr3,
                                                  float* __restrict__ rn_all,
                                                  int M) {
  __shared__ short Ahi_s[128][GBK + 8];
  __shared__ short Bhi_s[256][GBK + 8];
  __shared__ float nsq_s[128];
  const int w = blockIdx.z;
  const short* Bthi = Bthi_all + (size_t)w * 65536;
  unsigned short* C16 = (w == 0) ? ht16 : (w == 1) ? hr0 : (w == 2) ? hr1 : (w == 3) ? hr2 : hr3;
  const float* bias = (w == 0) ? bnb : nullptr;
  float* rn = rn_all + (size_t)w * N_NODES;

  const int t    = threadIdx.x;               // 0..511
  const int bm0  = blockIdx.x * GBM;
  const int wave = t >> 6, lane = t & 63;
  const int wm   = (wave >> 2) * 64;          // 0 or 64
  const int wn   = (wave & 3) * 64;           // 0,64,128,192
  const int m16  = lane & 15, kg = lane >> 4;

  if (t < 128) nsq_s[t] = 0.f;

  f32x4 acc[4][4] = {};

  const int arow = t >> 2, ac = t & 3;
  int agrow = bm0 + arow; if (agrow >= M) agrow = M - 1;
  const unsigned short* aptr = A16 + (size_t)agrow * 256 + ac * 8;
  const int brow0 = t >> 2, bc = t & 3;

  for (int k0 = 0; k0 < DIM; k0 += GBK) {
    *(us8*)&Ahi_s[arow][ac * 8] = *(const us8*)(aptr + k0);
    *(bf16x8*)&Bhi_s[brow0][bc * 8] =
        *(const bf16x8*)(Bthi + (size_t)brow0 * 256 + k0 + bc * 8);
    *(bf16x8*)&Bhi_s[brow0 + 128][bc * 8] =
        *(const bf16x8*)(Bthi + (size_t)(brow0 + 128) * 256 + k0 + bc * 8);
    __syncthreads();

    bf16x8 ah[4], bh[4];
#pragma unroll
    for (int i = 0; i < 4; i++) {
      ah[i] = *(const bf16x8*)&Ahi_s[wm + i * 16 + m16][kg * 8];
      bh[i] = *(const bf16x8*)&Bhi_s[wn + i * 16 + m16][kg * 8];
    }
#pragma unroll
    for (int mi = 0; mi < 4; mi++)
#pragma unroll
      for (int ni = 0; ni < 4; ni++)
        acc[mi][ni] = __builtin_amdgcn_mfma_f32_16x16x32_bf16(ah[mi], bh[ni], acc[mi][ni], 0, 0, 0);
    __syncthreads();
  }

#pragma unroll
  for (int mi = 0; mi < 4; mi++) {
    float ps[4] = {0.f, 0.f, 0.f, 0.f};
#pragma unroll
    for (int ni = 0; ni < 4; ni++) {
      int col = wn + ni * 16 + m16;
      float bb = bias ? bias[col] : 0.f;
      f32x4 v = acc[mi][ni];
#pragma unroll
      for (int j = 0; j < 4; j++) {
        float vj = v[j] + bb;
        int row = bm0 + wm + mi * 16 + kg * 4 + j;
        if (row < M) C16[(size_t)row * 256 + col] = f2bf_rne(vj);
        ps[j] += vj * vj;
      }
    }
#pragma unroll
    for (int j = 0; j < 4; j++) {
      float s = ps[j];
      s += __shfl_xor(s, 1);
      s += __shfl_xor(s, 2);
      s += __shfl_xor(s, 4);
      s += __shfl_xor(s, 8);
      if (m16 == 0) atomicAdd(&nsq_s[wm + mi * 16 + kg * 4 + j], s);
    }
  }
  __syncthreads();
  if (t < 128) {
    int row = bm0 + t;
    if (row < M) rn[row] = fminf(rsqrtf(nsq_s[t]), 1e8f);
  }
}

// ---- scan of TB bucket counts -> global bucket bases; also offsets[RN] ----
__global__ __launch_bounds__(1024) void k_bucket_scan(const int* __restrict__ cnt,
                                                      int* __restrict__ bbase,
                                                      int* __restrict__ offsets) {
  __shared__ int s[1024];
  int tid = threadIdx.x;
  int v = (tid < TB) ? cnt[tid] : 0;
  s[tid] = v;
  __syncthreads();
  for (int off = 1; off < 1024; off <<= 1) {
    int t2 = (tid >= off) ? s[tid - off] : 0;
    __syncthreads();
    s[tid] += t2;
    __syncthreads();
  }
  if (tid < TB) bbase[tid] = s[tid] - v;
  if (tid == TB - 1) offsets[RN] = s[tid];
}

// ---- per-bucket exact CSR (offsets + edge_src) ----
__global__ __launch_bounds__(256) void k_csr(const int* __restrict__ binned,
                                             const int* __restrict__ cnt_arr,
                                             const int* __restrict__ bbase,
                                             int* __restrict__ offsets,
                                             int* __restrict__ edge_src) {
  __shared__ int hist[256];
  __shared__ int excl[256];
  int b   = blockIdx.x;
  int tid = threadIdx.x;
  int cnt = cnt_arr[b]; if (cnt > BCAP) cnt = BCAP;
  int gbase = bbase[b];
  hist[tid] = 0;
  __syncthreads();
  const int* bp = binned + (size_t)b * BCAP;
  for (int i = tid; i < cnt; i += 256) atomicAdd(&hist[bp[i] & 255], 1);
  __syncthreads();
  int v = hist[tid];
  excl[tid] = v;
  __syncthreads();
  for (int off = 1; off < 256; off <<= 1) {
    int t2 = (tid >= off) ? excl[tid - off] : 0;
    __syncthreads();
    excl[tid] += t2;
    __syncthreads();
  }
  int ex = excl[tid] - v;                         // exclusive within bucket
  int r = b / NB, bloc = b % NB;
  int node = bloc * 256 + tid;
  if (node < N_NODES) offsets[r * N_NODES + node] = gbase + ex;
  hist[tid] = gbase + ex;                         // reuse as cursor
  __syncthreads();
  for (int i = tid; i < cnt; i += 256) {
    int p = bp[i];
    int pos = atomicAdd(&hist[p & 255], 1);
    edge_src[pos] = p >> 8;
  }
}

// ---- fused aggregation + final combine: one wave per dst node ----
// 16-lane group g owns relation g's edge list (1 edge/iter, 2-deep prefetch);
// lane owns 16 elements as 8 packed float2. For n>=NV the softmax combine is
// done in-register and written straight to out (non-temporal); h16/ma stored
// only for n<NV.
__global__ __launch_bounds__(256) void k_aggregate_fused(
    const unsigned short* __restrict__ hr0, const unsigned short* __restrict__ hr1,
    const unsigned short* __restrict__ hr2, const unsigned short* __restrict__ hr3,
    const unsigned short* __restrict__ ht16, const float* __restrict__ rn,
    const int* __restrict__ offsets, const int* __restrict__ edge_src,
    unsigned short* __restrict__ h16, float* __restrict__ ma,
    float* __restrict__ out) {
  int n    = (int)((blockIdx.x * (size_t)blockDim.x + threadIdx.x) >> 6);
  int lane = threadIdx.x & 63;
  if (n >= N_NODES) return;
  int g = lane >> 4, l16 = lane & 15;

  const u32x4* htp = (const u32x4*)(ht16 + (size_t)n * DIM + l16 * 16);
  u32x4 hta = __builtin_nontemporal_load(htp);
  u32x4 htb = __builtin_nontemporal_load(htp + 1);
  float rd = rn[n];
  f32x2 rd2 = {rd, rd};
  f32x2 hd2[8];
  hd2[0] = expand_bf2(hta[0]) * rd2; hd2[1] = expand_bf2(hta[1]) * rd2;
  hd2[2] = expand_bf2(hta[2]) * rd2; hd2[3] = expand_bf2(hta[3]) * rd2;
  hd2[4] = expand_bf2(htb[0]) * rd2; hd2[5] = expand_bf2(htb[1]) * rd2;
  hd2[6] = expand_bf2(htb[2]) * rd2; hd2[7] = expand_bf2(htb[3]) * rd2;

  const unsigned short* hr = (g == 0) ? hr0 : (g == 1) ? hr1 : (g == 2) ? hr2 : hr3;
  const float* nq = rn + (size_t)(1 + g) * N_NODES;
  int b   = offsets[g * N_NODES + n];
  int end = offsets[g * N_NODES + n + 1];

  f32x2 acc2[8] = {};
  float asum = 0.f;

  auto loadslot = [&](int i, uint4& ua, uint4& ub, float& q) {
    if (i < end) {
      int sn = edge_src[i];
      const uint4* rp = (const uint4*)(hr + (size_t)sn * DIM + l16 * 16);
      ua = rp[0]; ub = rp[1];
      q  = nq[sn];
    }
  };
  auto consume = [&](uint4 ua, uint4 ub, float q, bool valid) {
    f32x2 hs2[8];
    hs2[0] = expand_bf2(ua.x); hs2[1] = expand_bf2(ua.y);
    hs2[2] = expand_bf2(ua.z); hs2[3] = expand_bf2(ua.w);
    hs2[4] = expand_bf2(ub.x); hs2[5] = expand_bf2(ub.y);
    hs2[6] = expand_bf2(ub.z); hs2[7] = expand_bf2(ub.w);
    f32x2 d2 = hs2[0] * hd2[0];
#pragma unroll
    for (int i = 1; i < 8; i++) d2 += hs2[i] * hd2[i];
    float num = d2.x + d2.y;
    num += __shfl_xor(num, 1);
    num += __shfl_xor(num, 2);
    num += __shfl_xor(num, 4);
    num += __shfl_xor(num, 8);
    float s = valid ? num * q : 0.f;
    f32x2 s2 = {s, s};
#pragma unroll
    for (int i = 0; i < 8; i++) acc2[i] += hs2[i] * s2;
    asum += s;
  };

  uint4 uaA = {0,0,0,0}, ubA = {0,0,0,0}, uaB = {0,0,0,0}, ubB = {0,0,0,0};
  float qA = 1.f, qB = 1.f;
  loadslot(b,     uaA, ubA, qA);
  loadslot(b + 1, uaB, ubB, qB);
  for (int i = b; i < end; i += 2) {
    uint4 uaC = {0,0,0,0}, ubC = {0,0,0,0}, uaD = {0,0,0,0}, ubD = {0,0,0,0};
    float qC = 1.f, qD = 1.f;
    loadslot(i + 2, uaC, ubC, qC);
    loadslot(i + 3, uaD, ubD, qD);
    consume(uaA, ubA, qA, true);
    consume(uaB, ubB, qB, (i + 1) < end);
    uaA = uaC; ubA = ubC; qA = qC;
    uaB = uaD; ubB = ubD; qB = qD;
  }

  float mymean = asum / fmaxf((float)(end - b), 1.0f);

  if (n < NV_VUL) {
    us8 o1, o2;
#pragma unroll
    for (int i = 0; i < 4; i++) {
      o1[2 * i]     = f2bf_rne(acc2[i].x);
      o1[2 * i + 1] = f2bf_rne(acc2[i].y);
      o2[2 * i]     = f2bf_rne(acc2[4 + i].x);
      o2[2 * i + 1] = f2bf_rne(acc2[4 + i].y);
    }
    unsigned short* hp = h16 + ((size_t)n * R_REL + g) * DIM + l16 * 16;
    *(us8*)hp       = o1;
    *(us8*)(hp + 8) = o2;
    if (l16 == 0) ma[n * R_REL + g] = mymean;
  } else {
    // in-register softmax over the 4 groups' means
    float a1 = __shfl_xor(mymean, 16);
    float a2 = __shfl_xor(mymean, 32);
    float a3 = __shfl_xor(mymean, 48);
    float mx = fmaxf(fmaxf(mymean, a1), fmaxf(a2, a3));
    float e0 = expf(mymean - mx);
    float denom = e0 + expf(a1 - mx) + expf(a2 - mx) + expf(a3 - mx);
    float w = e0 / denom;
    f32x2 o[8];
#pragma unroll
    for (int i = 0; i < 8; i++) {
      f32x2 v = acc2[i] * (f32x2){w, w};
      v.x += __shfl_xor(v.x, 16); v.x += __shfl_xor(v.x, 32);
      v.y += __shfl_xor(v.y, 16); v.y += __shfl_xor(v.y, 32);
      o[i] = v;
    }
    if (g == 0) {
      float* op = out + (size_t)n * 256 + l16 * 16;
      f32x4 v0 = {o[0].x, o[0].y, o[1].x, o[1].y};
      f32x4 v1 = {o[2].x, o[2].y, o[3].x, o[3].y};
      f32x4 v2 = {o[4].x, o[4].y, o[5].x, o[5].y};
      f32x4 v3 = {o[6].x, o[6].y, o[7].x, o[7].y};
      __builtin_nontemporal_store(v0, (f32x4*)(op + 0));
      __builtin_nontemporal_store(v1, (f32x4*)(op + 4));
      __builtin_nontemporal_store(v2, (f32x4*)(op + 8));
      __builtin_nontemporal_store(v3, (f32x4*)(op + 12));
    }
  }
}

// ------- vulnerable nodes: mask + combine from bf16 h16 (NV rows only) -------
__global__ __launch_bounds__(256) void k_vuln_combine(const unsigned short* __restrict__ h16,
                                                      const int* __restrict__ cand,
                                                      const float* __restrict__ ma,
                                                      float* __restrict__ out) {
  __shared__ float red[8][4];
  __shared__ float dist2s[8];
  __shared__ float sm[1024];
  int n   = blockIdx.x;
  int tid = threadIdx.x;                       // owns elements tid*4 .. tid*4+3
  ushort4 hb = *(const ushort4*)(h16 + (size_t)n * 1024 + tid * 4);
  float4 hv;
  hv.x = bf2f(hb.x); hv.y = bf2f(hb.y); hv.z = bf2f(hb.z); hv.w = bf2f(hb.w);
  float4 d2[8];
  int wid = tid >> 6, lane = tid & 63;
#pragma unroll
  for (int k = 0; k < 8; k++) {
    int c = cand[n * 8 + k];
    ushort4 cb = *(const ushort4*)(h16 + (size_t)c * 1024 + tid * 4);
    float4 df;
    df.x = hv.x - bf2f(cb.x); df.y = hv.y - bf2f(cb.y);
    df.z = hv.z - bf2f(cb.z); df.w = hv.w - bf2f(cb.w);
    d2[k].x = df.x * df.x; d2[k].y = df.y * df.y;
    d2[k].z = df.z * df.z; d2[k].w = df.w * df.w;
    float v = d2[k].x + d2[k].y + d2[k].z + d2[k].w;
    for (int off = 32; off; off >>= 1) v += __shfl_xor(v, off);
    if (lane == 0) red[k][wid] = v;
  }
  __syncthreads();
  if (tid < 32) {
    int k = tid >> 2, w2 = tid & 3;
    float v = red[k][w2];
    v += __shfl_xor(v, 1, 4);
    v += __shfl_xor(v, 2, 4);
    if (w2 == 0) dist2s[k] = v;
  }
  __syncthreads();
  float dk[8], mn = 1e30f;
#pragma unroll
  for (int k = 0; k < 8; k++) { dk[k] = sqrtf(dist2s[k]); mn = fminf(mn, dk[k]); }
  float se = 0.f, att[8];
#pragma unroll
  for (int k = 0; k < 8; k++) { att[k] = expf(mn - dk[k]); se += att[k]; }
  float inv = 1.f / se;
  float4 accv = {0.f, 0.f, 0.f, 0.f};
#pragma unroll
  for (int k = 0; k < 8; k++) {
    float a = att[k] * inv;
    accv.x += a * d2[k].x; accv.y += a * d2[k].y;
    accv.z += a * d2[k].z; accv.w += a * d2[k].w;
  }
  float m0 = ma[n * 4 + 0], m1 = ma[n * 4 + 1], m2 = ma[n * 4 + 2], m3 = ma[n * 4 + 3];
  float mx = fmaxf(fmaxf(m0, m1), fmaxf(m2, m3));
  float w0 = expf(m0 - mx), w1 = expf(m1 - mx), w2f = expf(m2 - mx), w3 = expf(m3 - mx);
  float winv = 1.f / (w0 + w1 + w2f + w3);
  float wr = (tid < 64) ? w0 : (tid < 128) ? w1 : (tid < 192) ? w2f : w3;
  float c = wr * winv;
  float4 o;
  o.x = c * hv.x * expf(-accv.x);
  o.y = c * hv.y * expf(-accv.y);
  o.z = c * hv.z * expf(-accv.z);
  o.w = c * hv.w * expf(-accv.w);
  *(float4*)&sm[tid * 4] = o;
  __syncthreads();
  if (tid < 256) {
    float v = sm[tid] + sm[256 + tid] + sm[512 + tid] + sm[768 + tid];
    __builtin_nontemporal_store(v, out + (size_t)n * 256 + tid);
  }
}

// ---------------- diagnostic fallback ----------------
__global__ void k_fallback(float* __restrict__ out, int out_size, float wsmb) {
  int i = blockIdx.x * blockDim.x + threadIdx.x;
  if (i < out_size) out[i] = (i == 0) ? wsmb : 0.f;
}

extern "C" void kernel_launch(void* const* d_in, const int* in_sizes, int n_in,
                              void* d_out, int out_size, void* d_ws, size_t ws_size,
                              hipStream_t stream) {
  const float* x   = (const float*)d_in[0];
  const float* We  = (const float*)d_in[1];
  const float* Wn  = (const float*)d_in[2];
  const float* bnb = (const float*)d_in[3];
  const int* src   = (const int*)d_in[4];
  const int* dst   = (const int*)d_in[5];
  const int* cand  = (const int*)d_in[6];
  float* out = (float*)d_out;

  char* ws = (char*)d_ws;
  size_t off = 0;
  auto alloc = [&](size_t bytes) -> void* {
    void* p = ws + off;
    off += (bytes + 255) & ~(size_t)255;
    return p;
  };
  unsigned short* ht16        = (unsigned short*)alloc((size_t)N_NODES * DIM * 2);          // 25.6 MB
  unsigned short* h16         = (unsigned short*)alloc((size_t)NV_VUL * R_REL * DIM * 2);   // 20.5 MB
  float*          ma          = (float*)alloc((size_t)NV_VUL * R_REL * 4);
  float*          rn          = (float*)alloc((size_t)5 * N_NODES * 4);                     // reciprocal norms
  int*            bucket_cnt  = (int*)alloc((size_t)TB * 4);
  int*            bucket_base = (int*)alloc((size_t)TB * 4);
  int*            offsets     = (int*)alloc((size_t)(RN + 1) * 4);
  int*            edge_src    = (int*)alloc((size_t)R_REL * E_EDGES * 4);                   // 8 MB
  short*          Bthi        = (short*)alloc((size_t)5 * 65536 * 2);                       // 0.66 MB
  unsigned short* x16         = (unsigned short*)alloc((size_t)N_NODES * DIM * 2);          // 25.6 MB
  unsigned short* hr0         = (unsigned short*)alloc((size_t)N_NODES * DIM * 2);          // 25.6 MB
  unsigned short* hr1         = (unsigned short*)alloc((size_t)N_NODES * DIM * 2);          // 25.6 MB
  unsigned short* hr2         = (unsigned short*)alloc((size_t)N_NODES * DIM * 2);          // 25.6 MB
  unsigned short* hr3         = (unsigned short*)alloc((size_t)N_NODES * DIM * 2);          // 25.6 MB
  size_t required = off;
  (void)in_sizes; (void)n_in;

  if (ws_size < required) {
    k_fallback<<<(out_size + 255) / 256, 256, 0, stream>>>(out, out_size,
                                                           (float)(ws_size >> 20));
    return;
  }

  int* binned = (int*)h16;       // 16.06 MB bin staging aliases h16 (dead before aggregate)

  hipMemsetAsync(bucket_cnt, 0, (size_t)TB * 4, stream);

  // fused prep: weight convert | x convert | edge binning
  k_prep<<<PREP_W + PREP_X + PREP_BIN, 1024, 0, stream>>>(x, Wn, We, x16, Bthi,
                                                          src, dst, bucket_cnt, binned);
  k_bucket_scan<<<1, 1024, 0, stream>>>(bucket_cnt, bucket_base, offsets);
  k_csr<<<TB, 256, 0, stream>>>(binned, bucket_cnt, bucket_base, offsets, edge_src);

  // all 5 projections in one dispatch (z: 0 = ht16 w/ bias, 1..4 = hr[r]); 128x256 tile.
  // Reciprocal row norms computed in-kernel (LDS reduce) -> rn[w*N + row].
  dim3 gemm_grid((N_NODES + GBM - 1) / GBM, 1, 5);
  k_gemm_all<<<gemm_grid, 512, 0, stream>>>(x16, Bthi, bnb, ht16, hr0, hr1, hr2, hr3,
                                            rn, N_NODES);

  // fused aggregation + combine (writes h16/ma for n<NV, out rows [NV,N) directly)
  k_aggregate_fused<<<(N_NODES * 64 + 255) / 256, 256, 0, stream>>>(
      hr0, hr1, hr2, hr3, ht16, rn, offsets, edge_src, h16, ma, out);

  // vulnerable nodes: mask + combine (reads h16, writes out rows [0, NV))
  k_vuln_combine<<<NV_VUL, 256, 0, stream>>>(h16, cand, ma, out);
}

// Round 17
// 324.910 us; speedup vs baseline: 1.2914x; 1.0346x over previous
//
#include <hip/hip_runtime.h>

#define N_NODES 50000
#define DIM     256
#define R_REL   4
#define E_EDGES 500000
#define NV_VUL  10000
#define K_CAND  8
#define EPS_C   1e-8f
#define RN      (R_REL * N_NODES)            // 200000
#define NB      196                          // buckets per relation (256 nodes each)
#define TB      (R_REL * NB)                 // 784 total buckets
#define BCAP    5120                         // capacity per bucket (mean 2551)
#define EPB     4096                         // edges per bin block
#define PREP_W   80                          // convert_w blocks
#define PREP_X   128                         // convert_x blocks
#define PREP_BIN ((R_REL * E_EDGES + EPB - 1) / EPB)   // 489

#define GBM 128
#define GBK 32
#define GEMM_BLKS  ((N_NODES + GBM - 1) / GBM)   // 391
#define GEMM_TOTAL (GEMM_BLKS * 5)               // 1955

typedef short bf16x8 __attribute__((ext_vector_type(8)));
typedef float f32x4  __attribute__((ext_vector_type(4)));
typedef float f32x2  __attribute__((ext_vector_type(2)));
typedef unsigned short us8 __attribute__((ext_vector_type(8)));
typedef unsigned int u32x4 __attribute__((ext_vector_type(4)));

__device__ __forceinline__ unsigned short f2bf_rne(float f) {
  unsigned u = __builtin_bit_cast(unsigned, f);
  unsigned r = (u + 0x7FFFu + ((u >> 16) & 1u)) >> 16;
  return (unsigned short)r;
}
__device__ __forceinline__ float bf2f(unsigned short h) {
  unsigned u = ((unsigned)h) << 16;
  return __builtin_bit_cast(float, u);
}
// one dword holding 2 bf16 -> float2 {elem_lo, elem_hi}
__device__ __forceinline__ f32x2 expand_bf2(unsigned dw) {
  f32x2 v;
  v.x = __builtin_bit_cast(float, dw << 16);
  v.y = __builtin_bit_cast(float, dw & 0xFFFF0000u);
  return v;
}

// ---- fused prep: convert_w | convert_x | bin, partitioned by blockIdx.x ----
__global__ __launch_bounds__(1024) void k_prep(const float* __restrict__ x,
                                               const float* __restrict__ Wn,
                                               const float* __restrict__ We,
                                               unsigned short* __restrict__ x16,
                                               short* __restrict__ Bthi,
                                               const int* __restrict__ src,
                                               const int* __restrict__ dst,
                                               int* __restrict__ cursor,
                                               int* __restrict__ binned) {
  __shared__ float tile[64][65];
  __shared__ int hist[TB];
  __shared__ int base[TB];
  int blk = blockIdx.x;
  int tid = threadIdx.x;

  if (blk < PREP_W) {
    // ---- weight transpose+convert: Bthi[w][n][k] = bf16(W_w[k][n]) ----
    int w   = blk / 16;
    int rem = blk % 16;
    int k0  = (rem / 4) * 64, n0 = (rem % 4) * 64;
    const float* W = (w == 0) ? Wn : We + (size_t)(w - 1) * 65536;
    int tx = tid & 63, ty = tid >> 6;            // ty: 0..15
    for (int i = ty; i < 64; i += 16)
      tile[i][tx] = W[(size_t)(k0 + i) * 256 + n0 + tx];
    __syncthreads();
    for (int i = ty; i < 64; i += 16) {
      float f = tile[tx][i];                     // = W[k0+tx][n0+i]
      size_t o = (size_t)w * 65536 + (size_t)(n0 + i) * 256 + k0 + tx;
      Bthi[o] = (short)f2bf_rne(f);
    }
    return;
  }
  if (blk < PREP_W + PREP_X) {
    // ---- x fp32 -> bf16 (grid-stride over us8 chunks) ----
    const int total = N_NODES * DIM / 8;
    for (int i = (blk - PREP_W) * 1024 + tid; i < total; i += PREP_X * 1024) {
      float4 a = *(const float4*)(x + (size_t)i * 8);
      float4 b = *(const float4*)(x + (size_t)i * 8 + 4);
      us8 o;
      o[0] = f2bf_rne(a.x); o[1] = f2bf_rne(a.y); o[2] = f2bf_rne(a.z); o[3] = f2bf_rne(a.w);
      o[4] = f2bf_rne(b.x); o[5] = f2bf_rne(b.y); o[6] = f2bf_rne(b.z); o[7] = f2bf_rne(b.w);
      *(us8*)(x16 + (size_t)i * 8) = o;
    }
    return;
  }
  // ---- bin edges into TB coarse buckets; packed entry = (src<<8)|(dst&255) ----
  int bb = blk - PREP_W - PREP_X;
  for (int i = tid; i < TB; i += 1024) hist[i] = 0;
  __syncthreads();
  int e0 = bb * EPB;
  int myb[4], myrank[4], myp[4];
#pragma unroll
  for (int i = 0; i < 4; i++) {
    int e = e0 + i * 1024 + tid;
    myb[i] = -1;
    if (e < R_REL * E_EDGES) {
      int r = e / E_EDGES;
      int d = dst[e];
      int s = src[e];
      int b = r * NB + (d >> 8);
      myb[i]    = b;
      myp[i]    = (s << 8) | (d & 255);
      myrank[i] = atomicAdd(&hist[b], 1);
    }
  }
  __syncthreads();
  for (int i = tid; i < TB; i += 1024) {
    int c = hist[i];
    base[i] = c ? atomicAdd(&cursor[i], c) : 0;
  }
  __syncthreads();
#pragma unroll
  for (int i = 0; i < 4; i++) {
    if (myb[i] >= 0) {
      int pos = base[myb[i]] + myrank[i];
      if (pos < BCAP) binned[(size_t)myb[i] * BCAP + pos] = myp[i];
    }
  }
}

// ---- mega-dispatch: 5 GEMMs (blk < GEMM_TOTAL) | per-bucket CSR (rest) ----
// GEMM: 128x256 tile, 8 waves, fused reciprocal row norms (LDS reduce).
// CSR blocks compute their own bucket base via redundant prefix reduction,
// then build offsets + edge_src. Independent of GEMM -> fills CU slack.
__global__ __launch_bounds__(512) void k_gemm_csr(const unsigned short* __restrict__ A16,
                                                  const short* __restrict__ Bthi_all,
                                                  const float* __restrict__ bnb,
                                                  unsigned short* __restrict__ ht16,
                                                  unsigned short* __restrict__ hr0,
                                                  unsigned short* __restrict__ hr1,
                                                  unsigned short* __restrict__ hr2,
                                                  unsigned short* __restrict__ hr3,
                                                  float* __restrict__ rn_all,
                                                  const int* __restrict__ binned,
                                                  const int* __restrict__ cnt_arr,
                                                  int* __restrict__ offsets,
                                                  int* __restrict__ edge_src,
                                                  int M) {
  __shared__ short Ahi_s[128][GBK + 8];
  __shared__ short Bhi_s[256][GBK + 8];
  __shared__ float nsq_s[128];
  __shared__ int hist2[256];
  __shared__ int excl2[256];
  __shared__ int wred[8];
  const int blk = blockIdx.x;
  const int t   = threadIdx.x;                // 0..511

  if (blk < GEMM_TOTAL) {
    const int w  = blk / GEMM_BLKS;
    const int bx = blk % GEMM_BLKS;
    const short* Bthi = Bthi_all + (size_t)w * 65536;
    unsigned short* C16 = (w == 0) ? ht16 : (w == 1) ? hr0 : (w == 2) ? hr1 : (w == 3) ? hr2 : hr3;
    const float* bias = (w == 0) ? bnb : nullptr;
    float* rn = rn_all + (size_t)w * N_NODES;

    const int bm0  = bx * GBM;
    const int wave = t >> 6, lane = t & 63;
    const int wm   = (wave >> 2) * 64;          // 0 or 64
    const int wn   = (wave & 3) * 64;           // 0,64,128,192
    const int m16  = lane & 15, kg = lane >> 4;

    if (t < 128) nsq_s[t] = 0.f;

    f32x4 acc[4][4] = {};

    const int arow = t >> 2, ac = t & 3;
    int agrow = bm0 + arow; if (agrow >= M) agrow = M - 1;
    const unsigned short* aptr = A16 + (size_t)agrow * 256 + ac * 8;
    const int brow0 = t >> 2, bc = t & 3;

    for (int k0 = 0; k0 < DIM; k0 += GBK) {
      *(us8*)&Ahi_s[arow][ac * 8] = *(const us8*)(aptr + k0);
      *(bf16x8*)&Bhi_s[brow0][bc * 8] =
          *(const bf16x8*)(Bthi + (size_t)brow0 * 256 + k0 + bc * 8);
      *(bf16x8*)&Bhi_s[brow0 + 128][bc * 8] =
          *(const bf16x8*)(Bthi + (size_t)(brow0 + 128) * 256 + k0 + bc * 8);
      __syncthreads();

      bf16x8 ah[4], bh[4];
#pragma unroll
      for (int i = 0; i < 4; i++) {
        ah[i] = *(const bf16x8*)&Ahi_s[wm + i * 16 + m16][kg * 8];
        bh[i] = *(const bf16x8*)&Bhi_s[wn + i * 16 + m16][kg * 8];
      }
#pragma unroll
      for (int mi = 0; mi < 4; mi++)
#pragma unroll
        for (int ni = 0; ni < 4; ni++)
          acc[mi][ni] = __builtin_amdgcn_mfma_f32_16x16x32_bf16(ah[mi], bh[ni], acc[mi][ni], 0, 0, 0);
      __syncthreads();
    }

#pragma unroll
    for (int mi = 0; mi < 4; mi++) {
      float ps[4] = {0.f, 0.f, 0.f, 0.f};
#pragma unroll
      for (int ni = 0; ni < 4; ni++) {
        int col = wn + ni * 16 + m16;
        float bb = bias ? bias[col] : 0.f;
        f32x4 v = acc[mi][ni];
#pragma unroll
        for (int j = 0; j < 4; j++) {
          float vj = v[j] + bb;
          int row = bm0 + wm + mi * 16 + kg * 4 + j;
          if (row < M) C16[(size_t)row * 256 + col] = f2bf_rne(vj);
          ps[j] += vj * vj;
        }
      }
#pragma unroll
      for (int j = 0; j < 4; j++) {
        float s = ps[j];
        s += __shfl_xor(s, 1);
        s += __shfl_xor(s, 2);
        s += __shfl_xor(s, 4);
        s += __shfl_xor(s, 8);
        if (m16 == 0) atomicAdd(&nsq_s[wm + mi * 16 + kg * 4 + j], s);
      }
    }
    __syncthreads();
    if (t < 128) {
      int row = bm0 + t;
      if (row < M) rn[row] = fminf(rsqrtf(nsq_s[t]), 1e8f);
    }
    return;
  }

  // ---------------- CSR part ----------------
  const int b = blk - GEMM_TOTAL;              // bucket index 0..TB-1
  // gbase = prefix sum of cnt_arr[0..b) (redundant per block, cheap)
  int partial = 0;
  for (int i = t; i < b; i += 512) partial += cnt_arr[i];
  for (int off = 32; off; off >>= 1) partial += __shfl_xor(partial, off);
  if ((t & 63) == 0) wred[t >> 6] = partial;
  __syncthreads();
  if (t == 0) {
    int s = 0;
#pragma unroll
    for (int i = 0; i < 8; i++) s += wred[i];
    wred[0] = s;
    if (b == 0) offsets[RN] = R_REL * E_EDGES;   // grand total (no bucket overflow)
  }
  __syncthreads();
  const int gbase = wred[0];

  int cntb = cnt_arr[b]; if (cntb > BCAP) cntb = BCAP;
  if (t < 256) hist2[t] = 0;
  __syncthreads();
  const int* bp = binned + (size_t)b * BCAP;
  for (int i = t; i < cntb; i += 512) atomicAdd(&hist2[bp[i] & 255], 1);
  __syncthreads();
  int v = 0;
  if (t < 256) { v = hist2[t]; excl2[t] = v; }
  __syncthreads();
  for (int off = 1; off < 256; off <<= 1) {
    int t2 = (t < 256 && t >= off) ? excl2[t - off] : 0;
    __syncthreads();
    if (t < 256) excl2[t] += t2;
    __syncthreads();
  }
  if (t < 256) {
    int ex = excl2[t] - v;                       // exclusive within bucket
    int r = b / NB, bloc = b % NB;
    int node = bloc * 256 + t;
    if (node < N_NODES) offsets[r * N_NODES + node] = gbase + ex;
    hist2[t] = gbase + ex;                       // reuse as cursor
  }
  __syncthreads();
  for (int i = t; i < cntb; i += 512) {
    int p = bp[i];
    int pos = atomicAdd(&hist2[p & 255], 1);
    edge_src[pos] = p >> 8;
  }
}

// ---- fused aggregation + final combine: one wave per dst node ----
// 16-lane group g owns relation g's edge list (1 edge/iter, 2-deep prefetch);
// lane owns 16 elements as 8 packed float2. For n>=NV the softmax combine is
// done in-register and written straight to out (non-temporal); h16/ma stored
// only for n<NV.
__global__ __launch_bounds__(256) void k_aggregate_fused(
    const unsigned short* __restrict__ hr0, const unsigned short* __restrict__ hr1,
    const unsigned short* __restrict__ hr2, const unsigned short* __restrict__ hr3,
    const unsigned short* __restrict__ ht16, const float* __restrict__ rn,
    const int* __restrict__ offsets, const int* __restrict__ edge_src,
    unsigned short* __restrict__ h16, float* __restrict__ ma,
    float* __restrict__ out) {
  int n    = (int)((blockIdx.x * (size_t)blockDim.x + threadIdx.x) >> 6);
  int lane = threadIdx.x & 63;
  if (n >= N_NODES) return;
  int g = lane >> 4, l16 = lane & 15;

  const u32x4* htp = (const u32x4*)(ht16 + (size_t)n * DIM + l16 * 16);
  u32x4 hta = __builtin_nontemporal_load(htp);
  u32x4 htb = __builtin_nontemporal_load(htp + 1);
  float rd = rn[n];
  f32x2 rd2 = {rd, rd};
  f32x2 hd2[8];
  hd2[0] = expand_bf2(hta[0]) * rd2; hd2[1] = expand_bf2(hta[1]) * rd2;
  hd2[2] = expand_bf2(hta[2]) * rd2; hd2[3] = expand_bf2(hta[3]) * rd2;
  hd2[4] = expand_bf2(htb[0]) * rd2; hd2[5] = expand_bf2(htb[1]) * rd2;
  hd2[6] = expand_bf2(htb[2]) * rd2; hd2[7] = expand_bf2(htb[3]) * rd2;

  const unsigned short* hr = (g == 0) ? hr0 : (g == 1) ? hr1 : (g == 2) ? hr2 : hr3;
  const float* nq = rn + (size_t)(1 + g) * N_NODES;
  int b   = offsets[g * N_NODES + n];
  int end = offsets[g * N_NODES + n + 1];

  f32x2 acc2[8] = {};
  float asum = 0.f;

  auto loadslot = [&](int i, uint4& ua, uint4& ub, float& q) {
    if (i < end) {
      int sn = edge_src[i];
      const uint4* rp = (const uint4*)(hr + (size_t)sn * DIM + l16 * 16);
      ua = rp[0]; ub = rp[1];
      q  = nq[sn];
    }
  };
  auto consume = [&](uint4 ua, uint4 ub, float q, bool valid) {
    f32x2 hs2[8];
    hs2[0] = expand_bf2(ua.x); hs2[1] = expand_bf2(ua.y);
    hs2[2] = expand_bf2(ua.z); hs2[3] = expand_bf2(ua.w);
    hs2[4] = expand_bf2(ub.x); hs2[5] = expand_bf2(ub.y);
    hs2[6] = expand_bf2(ub.z); hs2[7] = expand_bf2(ub.w);
    f32x2 d2 = hs2[0] * hd2[0];
#pragma unroll
    for (int i = 1; i < 8; i++) d2 += hs2[i] * hd2[i];
    float num = d2.x + d2.y;
    num += __shfl_xor(num, 1);
    num += __shfl_xor(num, 2);
    num += __shfl_xor(num, 4);
    num += __shfl_xor(num, 8);
    float s = valid ? num * q : 0.f;
    f32x2 s2 = {s, s};
#pragma unroll
    for (int i = 0; i < 8; i++) acc2[i] += hs2[i] * s2;
    asum += s;
  };

  uint4 uaA = {0,0,0,0}, ubA = {0,0,0,0}, uaB = {0,0,0,0}, ubB = {0,0,0,0};
  float qA = 1.f, qB = 1.f;
  loadslot(b,     uaA, ubA, qA);
  loadslot(b + 1, uaB, ubB, qB);
  for (int i = b; i < end; i += 2) {
    uint4 uaC = {0,0,0,0}, ubC = {0,0,0,0}, uaD = {0,0,0,0}, ubD = {0,0,0,0};
    float qC = 1.f, qD = 1.f;
    loadslot(i + 2, uaC, ubC, qC);
    loadslot(i + 3, uaD, ubD, qD);
    consume(uaA, ubA, qA, true);
    consume(uaB, ubB, qB, (i + 1) < end);
    uaA = uaC; ubA = ubC; qA = qC;
    uaB = uaD; ubB = ubD; qB = qD;
  }

  float mymean = asum / fmaxf((float)(end - b), 1.0f);

  if (n < NV_VUL) {
    us8 o1, o2;
#pragma unroll
    for (int i = 0; i < 4; i++) {
      o1[2 * i]     = f2bf_rne(acc2[i].x);
      o1[2 * i + 1] = f2bf_rne(acc2[i].y);
      o2[2 * i]     = f2bf_rne(acc2[4 + i].x);
      o2[2 * i + 1] = f2bf_rne(acc2[4 + i].y);
    }
    unsigned short* hp = h16 + ((size_t)n * R_REL + g) * DIM + l16 * 16;
    *(us8*)hp       = o1;
    *(us8*)(hp + 8) = o2;
    if (l16 == 0) ma[n * R_REL + g] = mymean;
  } else {
    // in-register softmax over the 4 groups' means
    float a1 = __shfl_xor(mymean, 16);
    float a2 = __shfl_xor(mymean, 32);
    float a3 = __shfl_xor(mymean, 48);
    float mx = fmaxf(fmaxf(mymean, a1), fmaxf(a2, a3));
    float e0 = expf(mymean - mx);
    float denom = e0 + expf(a1 - mx) + expf(a2 - mx) + expf(a3 - mx);
    float w = e0 / denom;
    f32x2 o[8];
#pragma unroll
    for (int i = 0; i < 8; i++) {
      f32x2 v = acc2[i] * (f32x2){w, w};
      v.x += __shfl_xor(v.x, 16); v.x += __shfl_xor(v.x, 32);
      v.y += __shfl_xor(v.y, 16); v.y += __shfl_xor(v.y, 32);
      o[i] = v;
    }
    if (g == 0) {
      float* op = out + (size_t)n * 256 + l16 * 16;
      f32x4 v0 = {o[0].x, o[0].y, o[1].x, o[1].y};
      f32x4 v1 = {o[2].x, o[2].y, o[3].x, o[3].y};
      f32x4 v2 = {o[4].x, o[4].y, o[5].x, o[5].y};
      f32x4 v3 = {o[6].x, o[6].y, o[7].x, o[7].y};
      __builtin_nontemporal_store(v0, (f32x4*)(op + 0));
      __builtin_nontemporal_store(v1, (f32x4*)(op + 4));
      __builtin_nontemporal_store(v2, (f32x4*)(op + 8));
      __builtin_nontemporal_store(v3, (f32x4*)(op + 12));
    }
  }
}

// ------- vulnerable nodes: mask + combine from bf16 h16 (NV rows only) -------
__global__ __launch_bounds__(256) void k_vuln_combine(const unsigned short* __restrict__ h16,
                                                      const int* __restrict__ cand,
                                                      const float* __restrict__ ma,
                                                      float* __restrict__ out) {
  __shared__ float red[8][4];
  __shared__ float dist2s[8];
  __shared__ float sm[1024];
  int n   = blockIdx.x;
  int tid = threadIdx.x;                       // owns elements tid*4 .. tid*4+3
  ushort4 hb = *(const ushort4*)(h16 + (size_t)n * 1024 + tid * 4);
  float4 hv;
  hv.x = bf2f(hb.x); hv.y = bf2f(hb.y); hv.z = bf2f(hb.z); hv.w = bf2f(hb.w);
  float4 d2[8];
  int wid = tid >> 6, lane = tid & 63;
#pragma unroll
  for (int k = 0; k < 8; k++) {
    int c = cand[n * 8 + k];
    ushort4 cb = *(const ushort4*)(h16 + (size_t)c * 1024 + tid * 4);
    float4 df;
    df.x = hv.x - bf2f(cb.x); df.y = hv.y - bf2f(cb.y);
    df.z = hv.z - bf2f(cb.z); df.w = hv.w - bf2f(cb.w);
    d2[k].x = df.x * df.x; d2[k].y = df.y * df.y;
    d2[k].z = df.z * df.z; d2[k].w = df.w * df.w;
    float v = d2[k].x + d2[k].y + d2[k].z + d2[k].w;
    for (int off = 32; off; off >>= 1) v += __shfl_xor(v, off);
    if (lane == 0) red[k][wid] = v;
  }
  __syncthreads();
  if (tid < 32) {
    int k = tid >> 2, w2 = tid & 3;
    float v = red[k][w2];
    v += __shfl_xor(v, 1, 4);
    v += __shfl_xor(v, 2, 4);
    if (w2 == 0) dist2s[k] = v;
  }
  __syncthreads();
  float dk[8], mn = 1e30f;
#pragma unroll
  for (int k = 0; k < 8; k++) { dk[k] = sqrtf(dist2s[k]); mn = fminf(mn, dk[k]); }
  float se = 0.f, att[8];
#pragma unroll
  for (int k = 0; k < 8; k++) { att[k] = expf(mn - dk[k]); se += att[k]; }
  float inv = 1.f / se;
  float4 accv = {0.f, 0.f, 0.f, 0.f};
#pragma unroll
  for (int k = 0; k < 8; k++) {
    float a = att[k] * inv;
    accv.x += a * d2[k].x; accv.y += a * d2[k].y;
    accv.z += a * d2[k].z; accv.w += a * d2[k].w;
  }
  float m0 = ma[n * 4 + 0], m1 = ma[n * 4 + 1], m2 = ma[n * 4 + 2], m3 = ma[n * 4 + 3];
  float mx = fmaxf(fmaxf(m0, m1), fmaxf(m2, m3));
  float w0 = expf(m0 - mx), w1 = expf(m1 - mx), w2f = expf(m2 - mx), w3 = expf(m3 - mx);
  float winv = 1.f / (w0 + w1 + w2f + w3);
  float wr = (tid < 64) ? w0 : (tid < 128) ? w1 : (tid < 192) ? w2f : w3;
  float c = wr * winv;
  float4 o;
  o.x = c * hv.x * expf(-accv.x);
  o.y = c * hv.y * expf(-accv.y);
  o.z = c * hv.z * expf(-accv.z);
  o.w = c * hv.w * expf(-accv.w);
  *(float4*)&sm[tid * 4] = o;
  __syncthreads();
  if (tid < 256) {
    float v = sm[tid] + sm[256 + tid] + sm[512 + tid] + sm[768 + tid];
    __builtin_nontemporal_store(v, out + (size_t)n * 256 + tid);
  }
}

// ---------------- diagnostic fallback ----------------
__global__ void k_fallback(float* __restrict__ out, int out_size, float wsmb) {
  int i = blockIdx.x * blockDim.x + threadIdx.x;
  if (i < out_size) out[i] = (i == 0) ? wsmb : 0.f;
}

extern "C" void kernel_launch(void* const* d_in, const int* in_sizes, int n_in,
                              void* d_out, int out_size, void* d_ws, size_t ws_size,
                              hipStream_t stream) {
  const float* x   = (const float*)d_in[0];
  const float* We  = (const float*)d_in[1];
  const float* Wn  = (const float*)d_in[2];
  const float* bnb = (const float*)d_in[3];
  const int* src   = (const int*)d_in[4];
  const int* dst   = (const int*)d_in[5];
  const int* cand  = (const int*)d_in[6];
  float* out = (float*)d_out;

  char* ws = (char*)d_ws;
  size_t off = 0;
  auto alloc = [&](size_t bytes) -> void* {
    void* p = ws + off;
    off += (bytes + 255) & ~(size_t)255;
    return p;
  };
  unsigned short* ht16        = (unsigned short*)alloc((size_t)N_NODES * DIM * 2);          // 25.6 MB
  unsigned short* h16         = (unsigned short*)alloc((size_t)NV_VUL * R_REL * DIM * 2);   // 20.5 MB
  float*          ma          = (float*)alloc((size_t)NV_VUL * R_REL * 4);
  float*          rn          = (float*)alloc((size_t)5 * N_NODES * 4);                     // reciprocal norms
  int*            bucket_cnt  = (int*)alloc((size_t)TB * 4);
  int*            offsets     = (int*)alloc((size_t)(RN + 1) * 4);
  int*            edge_src    = (int*)alloc((size_t)R_REL * E_EDGES * 4);                   // 8 MB
  short*          Bthi        = (short*)alloc((size_t)5 * 65536 * 2);                       // 0.66 MB
  unsigned short* x16         = (unsigned short*)alloc((size_t)N_NODES * DIM * 2);          // 25.6 MB
  unsigned short* hr0         = (unsigned short*)alloc((size_t)N_NODES * DIM * 2);          // 25.6 MB
  unsigned short* hr1         = (unsigned short*)alloc((size_t)N_NODES * DIM * 2);          // 25.6 MB
  unsigned short* hr2         = (unsigned short*)alloc((size_t)N_NODES * DIM * 2);          // 25.6 MB
  unsigned short* hr3         = (unsigned short*)alloc((size_t)N_NODES * DIM * 2);          // 25.6 MB
  size_t required = off;
  (void)in_sizes; (void)n_in;

  if (ws_size < required) {
    k_fallback<<<(out_size + 255) / 256, 256, 0, stream>>>(out, out_size,
                                                           (float)(ws_size >> 20));
    return;
  }

  int* binned = (int*)h16;       // 16.06 MB bin staging aliases h16 (dead before aggregate)

  hipMemsetAsync(bucket_cnt, 0, (size_t)TB * 4, stream);

  // fused prep: weight convert | x convert | edge binning
  k_prep<<<PREP_W + PREP_X + PREP_BIN, 1024, 0, stream>>>(x, Wn, We, x16, Bthi,
                                                          src, dst, bucket_cnt, binned);

  // mega-dispatch: 5 GEMMs (fused rnorm) + per-bucket CSR build (independent work)
  k_gemm_csr<<<GEMM_TOTAL + TB, 512, 0, stream>>>(x16, Bthi, bnb, ht16,
                                                  hr0, hr1, hr2, hr3, rn,
                                                  binned, bucket_cnt, offsets, edge_src,
                                                  N_NODES);

  // fused aggregation + combine (writes h16/ma for n<NV, out rows [NV,N) directly)
  k_aggregate_fused<<<(N_NODES * 64 + 255) / 256, 256, 0, stream>>>(
      hr0, hr1, hr2, hr3, ht16, rn, offsets, edge_src, h16, ma, out);

  // vulnerable nodes: mask + combine (reads h16, writes out rows [0, NV))
  k_vuln_combine<<<NV_VUL, 256, 0, stream>>>(h16, cand, ma, out);
}